// Round 1
// baseline (542.883 us; speedup 1.0000x reference)
//
#include <hip/hip_runtime.h>

typedef unsigned short u16;
typedef unsigned int u32;
typedef __attribute__((ext_vector_type(8))) __bf16 bf16x8;
typedef __attribute__((ext_vector_type(4))) float f32x4;
typedef __attribute__((ext_vector_type(8))) unsigned short u16x8;

typedef const __attribute__((address_space(1))) u32 gu32;
typedef __attribute__((address_space(3))) u32 lu32;

// fp32 -> bf16 round-to-nearest-even
__device__ __forceinline__ u16 f2b(float f) {
  u32 u = __builtin_bit_cast(u32, f);
  u32 r = u + 0x7fffu + ((u >> 16) & 1u);
  return (u16)(r >> 16);
}

// packed fp32 pair -> bf16 pair (RNE), hi in [31:16]
__device__ __forceinline__ u32 pk2(float lo, float hi) {
  u32 d;
  asm("v_cvt_pk_bf16_f32 %0, %1, %2" : "=v"(d) : "v"(lo), "v"(hi));
  return d;
}

__device__ __forceinline__ bf16x8 ld8(const u16* p) {
  return __builtin_bit_cast(bf16x8, *(const u16x8*)p);
}

__device__ __forceinline__ void gll16(const void* g, void* l) {
  __builtin_amdgcn_global_load_lds((gu32*)g, (lu32*)l, 16, 0, 0);
}

__device__ __forceinline__ f32x4 mfma16(bf16x8 a, bf16x8 b, f32x4 c) {
  return __builtin_amdgcn_mfma_f32_16x16x32_bf16(a, b, c, 0, 0, 0);
}

// ---------------- fp32 -> bf16 elementwise ----------------
__global__ void k_cvt(const float* __restrict__ in, u16* __restrict__ out, int n4) {
  int i = blockIdx.x * blockDim.x + threadIdx.x;
  int stride = gridDim.x * blockDim.x;
  for (int idx = i; idx < n4; idx += stride) {
    float4 v = ((const float4*)in)[idx];
    u32 lo = (u32)f2b(v.x) | ((u32)f2b(v.y) << 16);
    u32 hi = (u32)f2b(v.z) | ((u32)f2b(v.w) << 16);
    ((uint2*)out)[idx] = make_uint2(lo, hi);
  }
}

// ---------------- transpose+convert: in[R][C] f32 -> out[C][R] bf16 ----------------
__global__ void k_tr(const float* __restrict__ in, u16* __restrict__ out, int R, int C) {
  __shared__ u16 tile[32][33];
  int bx = blockIdx.x * 32;  // along C
  int by = blockIdx.y * 32;  // along R
  int tx = threadIdx.x, ty = threadIdx.y;  // (32, 8)
#pragma unroll
  for (int i = 0; i < 32; i += 8)
    tile[ty + i][tx] = f2b(in[(size_t)(by + ty + i) * C + bx + tx]);
  __syncthreads();
#pragma unroll
  for (int i = 0; i < 32; i += 8)
    out[(size_t)(bx + ty + i) * R + by + tx] = tile[tx][ty + i];
}

// ---------------- GEMM: A[M][1024] * B^T (B given as [N][1024]), 128x128 tile ----------------
// EPI=0: scatter bf16 into q/k/v [B=4][H=16][T=2048][64]; EPI=1: fp32 out [M][1024]
template <int EPI>
__global__ __launch_bounds__(256) void k_gemm(const u16* __restrict__ A,
                                              const u16* __restrict__ B,
                                              void* __restrict__ Cp) {
  const int K = 1024;
  __shared__ __align__(16) u16 As[128 * 32];
  __shared__ __align__(16) u16 Bs[128 * 32];
  int tid = threadIdx.x;
  int lane = tid & 63, wid = tid >> 6;
  int wr = wid >> 1, wc = wid & 1;
  int m0 = blockIdx.y * 128, n0 = blockIdx.x * 128;
  int r = lane & 15, qq = lane >> 4;

  const u16* Ag0 = A + (size_t)(m0 + wid * 32 + (lane >> 2)) * K + (lane & 3) * 8;
  const u16* Bg0 = B + (size_t)(n0 + wid * 32 + (lane >> 2)) * K + (lane & 3) * 8;
  u16* Asl0 = As + (wid * 32) * 32;
  u16* Asl1 = As + (wid * 32 + 16) * 32;
  u16* Bsl0 = Bs + (wid * 32) * 32;
  u16* Bsl1 = Bs + (wid * 32 + 16) * 32;

  f32x4 acc[4][4] = {};

  for (int k0 = 0; k0 < K; k0 += 32) {
    gll16(Ag0 + k0, Asl0);
    gll16(Ag0 + 16 * K + k0, Asl1);
    gll16(Bg0 + k0, Bsl0);
    gll16(Bg0 + 16 * K + k0, Bsl1);
    __syncthreads();
    bf16x8 af[4], bfr[4];
#pragma unroll
    for (int m = 0; m < 4; ++m) af[m] = ld8(&As[(wr * 64 + m * 16 + r) * 32 + qq * 8]);
#pragma unroll
    for (int n = 0; n < 4; ++n) bfr[n] = ld8(&Bs[(wc * 64 + n * 16 + r) * 32 + qq * 8]);
#pragma unroll
    for (int m = 0; m < 4; ++m)
#pragma unroll
      for (int n = 0; n < 4; ++n) acc[m][n] = mfma16(af[m], bfr[n], acc[m][n]);
    __syncthreads();
  }

  if constexpr (EPI == 0) {
    u16* qkv = (u16*)Cp;
#pragma unroll
    for (int m = 0; m < 4; ++m) {
      int gr = m0 + wr * 64 + m * 16 + qq * 4;
      int b = gr >> 11, t0 = gr & 2047;
#pragma unroll
      for (int n = 0; n < 4; ++n) {
        int gc = n0 + wc * 64 + n * 16 + r;
        int which = gc >> 10, rem = gc & 1023;
        int hh = rem >> 6, d = rem & 63;
        u16* dst = qkv + (size_t)which * 8388608u +
                   ((size_t)((b * 16 + hh) * 2048 + t0)) * 64 + d;
#pragma unroll
        for (int i = 0; i < 4; ++i) dst[(size_t)i * 64] = f2b(acc[m][n][i]);
      }
    }
  } else {
    float* out = (float*)Cp;
#pragma unroll
    for (int m = 0; m < 4; ++m) {
      int gr = m0 + wr * 64 + m * 16 + qq * 4;
#pragma unroll
      for (int n = 0; n < 4; ++n) {
        int gc = n0 + wc * 64 + n * 16 + r;
#pragma unroll
        for (int i = 0; i < 4; ++i) out[(size_t)(gr + i) * 1024 + gc] = acc[m][n][i];
      }
    }
  }
}

// ---------------- flash attention v2 (pipelined) ----------------
// q,k,v [B*H][2048][64] bf16 -> y [B][2048][1024] bf16
// grid: x = 16 q-blocks of 128 rows (REVERSED: x=0 -> longest), y = B*H = 64.
// 4 waves x 32 q-rows. KV tile = 64 keys.
// Pipelining (T14 async-split): tile it+1's K and V are loaded global->reg
// DURING compute of tile it; written to (single-buffered) LDS after the next
// barrier. The __syncthreads vmcnt(0) drain then lands a full compute phase
// after issue -> global latency hidden. LDS stays 33 KB -> 4 blocks/CU.
// K LDS layout: row-major [64][64] with 16B-slot XOR swizzle (slot ^= row&7),
// achieved by XOR-ing the GLOBAL load offset and writing LDS linearly
// (ds_write_b128, conflict-free).
// V LDS: transposed [d=64][72] (padded) via reg-staged u16 writes.
// P LDS: per-wave [32][64] with slot XOR swizzle; packed bf16 via v_cvt_pk.
// Softmax VALU diet: per-lane partial row-sums (cross-lane reduce ONCE in the
// epilogue), causal mask only on diagonal tiles, rescale skipped when the
// running max did not grow (bit-identical: corr would be exactly 1).
__global__ __launch_bounds__(256, 4) void k_attn(const u16* __restrict__ Qm,
                                                 const u16* __restrict__ Km,
                                                 const u16* __restrict__ Vm,
                                                 u16* __restrict__ Y) {
  int bh = blockIdx.y;
  int b = bh >> 4, h = bh & 15;
  int qb0 = (gridDim.x - 1 - blockIdx.x) * 128;  // longest blocks first
  int tid = threadIdx.x, lane = tid & 63, w = tid >> 6;
  int r = lane & 15, qq = lane >> 4;
  __shared__ __align__(16) u16 Ks[64 * 64];     // [key][64], slots XOR-swizzled
  __shared__ __align__(16) u16 Vt[64 * 72];     // [d][key] padded rows
  __shared__ __align__(16) u16 Ps[4][32 * 64];  // per-wave P, slot-swizzled
  const size_t basekv = (size_t)bh * (2048 * 64);
  int q0w = qb0 + w * 32;  // this wave's first q row (global)

  // Q fragments: rows m*16+r, k-slices kc*32+qq*8
  bf16x8 qf[2][2];
#pragma unroll
  for (int m = 0; m < 2; ++m)
#pragma unroll
    for (int kc = 0; kc < 2; ++kc)
      qf[m][kc] = ld8(Qm + basekv + (size_t)(q0w + m * 16 + r) * 64 + kc * 32 + qq * 8);

  f32x4 acc[2][4] = {};
  float m_run[2][4], l_run[2][4];  // l_run: PER-LANE partial sums (keys this lane owns)
#pragma unroll
  for (int m = 0; m < 2; ++m)
#pragma unroll
    for (int i = 0; i < 4; ++i) { m_run[m][i] = -1e30f; l_run[m][i] = 0.f; }
  const float csc = 0.125f * 1.44269504089f;  // 1/sqrt(64) * log2(e)
  int ntiles = (qb0 >> 6) + 2;  // uniform across waves -> barriers safe

  // K staging: wave w stages tile rows w*16..w*16+15.
  // lane covers row w*16 + c*8 + krow, global 16B chunk (kchunk ^ krow)
  // (swizzle on the LOAD side; LDS write is LINEAR -> conflict-free b128).
  int krow = lane >> 3, kchunk = lane & 7;
  const u16* Kg = Km + basekv + (size_t)(w * 16 + krow) * 64 + ((kchunk ^ krow) * 8);
  const u16* Vg = Vm + basekv;

  u16x8 kreg[2], vreg[2];
  // prologue: load tile 0 into regs
  kreg[0] = *(const u16x8*)(Kg);
  kreg[1] = *(const u16x8*)(Kg + (size_t)8 * 64);
  {
    const u16* vp = Vg + (size_t)lane * 64;
    vreg[0] = *(const u16x8*)(vp + w * 8);
    vreg[1] = *(const u16x8*)(vp + (w + 4) * 8);
  }

  for (int it = 0; it < ntiles; ++it) {
    int j0 = it << 6;
    __syncthreads();  // all waves done reading previous tile; drains vmcnt -> regs ready
    // store staged tile it (K linear b128 writes; layout slot s holds chunk s^row&7)
    *(u16x8*)&Ks[(w * 16 + krow) * 64 + kchunk * 8] = kreg[0];
    *(u16x8*)&Ks[(w * 16 + 8 + krow) * 64 + kchunk * 8] = kreg[1];
#pragma unroll
    for (int jj = 0; jj < 8; ++jj) Vt[(w * 8 + jj) * 72 + lane] = vreg[0][jj];
#pragma unroll
    for (int jj = 0; jj < 8; ++jj) Vt[((w + 4) * 8 + jj) * 72 + lane] = vreg[1][jj];
    __syncthreads();  // LDS tile visible to all waves

    // prefetch tile it+1 global->reg (completes during compute below)
    if (it + 1 < ntiles) {
      size_t joff = (size_t)(j0 + 64) * 64;
      kreg[0] = *(const u16x8*)(Kg + joff);
      kreg[1] = *(const u16x8*)(Kg + joff + (size_t)8 * 64);
      const u16* vp = Vg + joff + (size_t)lane * 64;
      vreg[0] = *(const u16x8*)(vp + w * 8);
      vreg[1] = *(const u16x8*)(vp + (w + 4) * 8);
    }

    if (j0 <= q0w + 31) {  // wave-uniform: skip fully-masked tiles
      // S = Q K^T
      f32x4 s[2][4] = {};
#pragma unroll
      for (int nt = 0; nt < 4; ++nt)
#pragma unroll
        for (int kc = 0; kc < 2; ++kc) {
          bf16x8 kf = ld8(&Ks[(nt * 16 + r) * 64 + (((kc * 4 + qq) ^ (r & 7)) * 8)]);
#pragma unroll
          for (int m = 0; m < 2; ++m) s[m][nt] = mfma16(qf[m][kc], kf, s[m][nt]);
        }

      // scale (log2 domain); causal mask only on diagonal tiles (wave-uniform branch)
      bool nm = (j0 + 63 > q0w);
      if (nm) {
#pragma unroll
        for (int m = 0; m < 2; ++m)
#pragma unroll
          for (int nt = 0; nt < 4; ++nt)
#pragma unroll
            for (int i = 0; i < 4; ++i) {
              int qg = q0w + m * 16 + qq * 4 + i;
              int kg = j0 + nt * 16 + r;
              s[m][nt][i] = (kg <= qg) ? s[m][nt][i] * csc : -1e30f;
            }
      } else {
#pragma unroll
        for (int m = 0; m < 2; ++m)
#pragma unroll
          for (int nt = 0; nt < 4; ++nt)
#pragma unroll
            for (int i = 0; i < 4; ++i) s[m][nt][i] *= csc;
      }

      // row max: fold nt in-lane, then across the 16 r-lanes
      float tm[2][4];
#pragma unroll
      for (int m = 0; m < 2; ++m)
#pragma unroll
        for (int i = 0; i < 4; ++i)
          tm[m][i] = fmaxf(fmaxf(s[m][0][i], s[m][1][i]), fmaxf(s[m][2][i], s[m][3][i]));
#pragma unroll
      for (int d = 1; d < 16; d <<= 1)
#pragma unroll
        for (int m = 0; m < 2; ++m)
#pragma unroll
          for (int i = 0; i < 4; ++i) tm[m][i] = fmaxf(tm[m][i], __shfl_xor(tm[m][i], d));

      // rescale only if the running max grew (corr would be exactly 1 otherwise)
      int growf = 0;
#pragma unroll
      for (int m = 0; m < 2; ++m)
#pragma unroll
        for (int i = 0; i < 4; ++i) growf |= (tm[m][i] > m_run[m][i]) ? 1 : 0;
      if (__any(growf)) {
#pragma unroll
        for (int m = 0; m < 2; ++m)
#pragma unroll
          for (int i = 0; i < 4; ++i) {
            float mn = fmaxf(m_run[m][i], tm[m][i]);
            float corr = exp2f(m_run[m][i] - mn);
            m_run[m][i] = mn;
            l_run[m][i] *= corr;
#pragma unroll
            for (int n = 0; n < 4; ++n) acc[m][n][i] *= corr;
          }
      }

      // P = exp2(S - m); accumulate per-lane partial row sums (no cross-lane reduce)
#pragma unroll
      for (int m = 0; m < 2; ++m)
#pragma unroll
        for (int i = 0; i < 4; ++i) {
          float ls = 0.f;
#pragma unroll
          for (int nt = 0; nt < 4; ++nt) {
            float e = exp2f(s[m][nt][i] - m_run[m][i]);
            s[m][nt][i] = e;
            ls += e;
          }
          l_run[m][i] += ls;
        }

      // P -> per-wave LDS (swizzled) via packed bf16 cvt; wave-local fence; re-read
#pragma unroll
      for (int m = 0; m < 2; ++m)
#pragma unroll
        for (int nt = 0; nt < 4; ++nt) {
          int key = nt * 16 + r;
          int kb = key >> 3, kl = key & 7;
#pragma unroll
          for (int ii = 0; ii < 4; ii += 2) {
            u32 pk = pk2(s[m][nt][ii], s[m][nt][ii + 1]);
            int ql0 = m * 16 + qq * 4 + ii;
            int ql1 = ql0 + 1;
            Ps[w][ql0 * 64 + ((kb ^ (ql0 & 7)) * 8) + kl] = (u16)pk;
            Ps[w][ql1 * 64 + ((kb ^ (ql1 & 7)) * 8) + kl] = (u16)(pk >> 16);
          }
        }
      asm volatile("s_waitcnt lgkmcnt(0)" ::: "memory");  // wave-local LDS RAW fence

      bf16x8 vfr[4][2];
#pragma unroll
      for (int n = 0; n < 4; ++n)
#pragma unroll
        for (int kc = 0; kc < 2; ++kc)
          vfr[n][kc] = ld8(&Vt[(n * 16 + r) * 72 + kc * 32 + qq * 8]);
#pragma unroll
      for (int m = 0; m < 2; ++m) {
        bf16x8 pf[2];
#pragma unroll
        for (int kc = 0; kc < 2; ++kc)
          pf[kc] = ld8(&Ps[w][(m * 16 + r) * 64 + (((kc * 4 + qq) ^ (r & 7)) * 8)]);
#pragma unroll
        for (int n = 0; n < 4; ++n)
#pragma unroll
          for (int kc = 0; kc < 2; ++kc)
            acc[m][n] = mfma16(pf[kc], vfr[n][kc], acc[m][n]);
      }
    }
  }

  // epilogue: reduce per-lane partial sums across the 16 r-lanes (once)
#pragma unroll
  for (int d = 1; d < 16; d <<= 1)
#pragma unroll
    for (int m = 0; m < 2; ++m)
#pragma unroll
      for (int i = 0; i < 4; ++i) l_run[m][i] += __shfl_xor(l_run[m][i], d);

  float inv[2][4];
#pragma unroll
  for (int m = 0; m < 2; ++m)
#pragma unroll
    for (int i = 0; i < 4; ++i) inv[m][i] = 1.0f / l_run[m][i];
#pragma unroll
  for (int m = 0; m < 2; ++m)
#pragma unroll
    for (int n = 0; n < 4; ++n)
#pragma unroll
      for (int i = 0; i < 4; ++i)
        Y[((size_t)(b * 2048 + q0w + m * 16 + qq * 4 + i)) * 1024 + h * 64 + n * 16 + r] =
            f2b(acc[m][n][i] * inv[m][i]);
}

// ---------------- launch ----------------
extern "C" void kernel_launch(void* const* d_in, const int* in_sizes, int n_in,
                              void* d_out, int out_size, void* d_ws, size_t ws_size,
                              hipStream_t stream) {
  const float* x = (const float*)d_in[0];       // [4,2048,1024]
  const float* w_attn = (const float*)d_in[1];  // [1024,3072]
  const float* w_o = (const float*)d_in[2];     // [1024,1024]
  float* out = (float*)d_out;                   // [4,2048,1024]

  char* ws = (char*)d_ws;
  u16* xb = (u16*)(ws + 0);                    // [8192][1024]        16,777,216 B
  u16* watT = (u16*)(ws + 16777216);           // [3072][1024]         6,291,456 B
  u16* woT = (u16*)(ws + 23068672);            // [1024][1024]         2,097,152 B
  u16* qb = (u16*)(ws + 25165824);             // q [4][16][2048][64] 16,777,216 B
  u16* kb = (u16*)(ws + 41943040);             // k                   16,777,216 B
  u16* vb = (u16*)(ws + 58720256);             // v                   16,777,216 B
  u16* yb = (u16*)(ws + 75497472);             // y [4][2048][1024]   16,777,216 B

  k_cvt<<<2048, 256, 0, stream>>>(x, xb, 8192 * 1024 / 4);
  k_tr<<<dim3(3072 / 32, 1024 / 32), dim3(32, 8), 0, stream>>>(w_attn, watT, 1024, 3072);
  k_tr<<<dim3(1024 / 32, 1024 / 32), dim3(32, 8), 0, stream>>>(w_o, woT, 1024, 1024);
  k_gemm<0><<<dim3(24, 64), 256, 0, stream>>>(xb, watT, (void*)qb);
  k_attn<<<dim3(16, 64), 256, 0, stream>>>(qb, kb, vb, yb);
  k_gemm<1><<<dim3(8, 64), 256, 0, stream>>>(yb, woT, (void*)out);
}

// Round 2
// 335.476 us; speedup vs baseline: 1.6182x; 1.6182x over previous
//
#include <hip/hip_runtime.h>

typedef unsigned short u16;
typedef unsigned int u32;
typedef __attribute__((ext_vector_type(8))) __bf16 bf16x8;
typedef __attribute__((ext_vector_type(4))) float f32x4;
typedef __attribute__((ext_vector_type(8))) unsigned short u16x8;

typedef const __attribute__((address_space(1))) u32 gu32;
typedef __attribute__((address_space(3))) u32 lu32;

// fp32 -> bf16 round-to-nearest-even
__device__ __forceinline__ u16 f2b(float f) {
  u32 u = __builtin_bit_cast(u32, f);
  u32 r = u + 0x7fffu + ((u >> 16) & 1u);
  return (u16)(r >> 16);
}

// packed fp32 pair -> bf16 pair (RNE), hi in [31:16]
__device__ __forceinline__ u32 pk2(float lo, float hi) {
  u32 d;
  asm("v_cvt_pk_bf16_f32 %0, %1, %2" : "=v"(d) : "v"(lo), "v"(hi));
  return d;
}

__device__ __forceinline__ bf16x8 ld8(const u16* p) {
  return __builtin_bit_cast(bf16x8, *(const u16x8*)p);
}

__device__ __forceinline__ void gll16(const void* g, void* l) {
  __builtin_amdgcn_global_load_lds((gu32*)g, (lu32*)l, 16, 0, 0);
}

__device__ __forceinline__ f32x4 mfma16(bf16x8 a, bf16x8 b, f32x4 c) {
  return __builtin_amdgcn_mfma_f32_16x16x32_bf16(a, b, c, 0, 0, 0);
}

// ---------------- fp32 -> bf16 elementwise ----------------
__global__ void k_cvt(const float* __restrict__ in, u16* __restrict__ out, int n4) {
  int i = blockIdx.x * blockDim.x + threadIdx.x;
  int stride = gridDim.x * blockDim.x;
  for (int idx = i; idx < n4; idx += stride) {
    float4 v = ((const float4*)in)[idx];
    u32 lo = (u32)f2b(v.x) | ((u32)f2b(v.y) << 16);
    u32 hi = (u32)f2b(v.z) | ((u32)f2b(v.w) << 16);
    ((uint2*)out)[idx] = make_uint2(lo, hi);
  }
}

// ---------------- transpose+convert: in[R][C] f32 -> out[C][R] bf16 ----------------
__global__ void k_tr(const float* __restrict__ in, u16* __restrict__ out, int R, int C) {
  __shared__ u16 tile[32][33];
  int bx = blockIdx.x * 32;  // along C
  int by = blockIdx.y * 32;  // along R
  int tx = threadIdx.x, ty = threadIdx.y;  // (32, 8)
#pragma unroll
  for (int i = 0; i < 32; i += 8)
    tile[ty + i][tx] = f2b(in[(size_t)(by + ty + i) * C + bx + tx]);
  __syncthreads();
#pragma unroll
  for (int i = 0; i < 32; i += 8)
    out[(size_t)(bx + ty + i) * R + by + tx] = tile[tx][ty + i];
}

// ---------------- GEMM: A[M][1024] * B^T (B given as [N][1024]), 128x128 tile ----------------
// EPI=0: scatter bf16 into q/k/v [B=4][H=16][T=2048][64]; EPI=1: fp32 out [M][1024]
template <int EPI>
__global__ __launch_bounds__(256) void k_gemm(const u16* __restrict__ A,
                                              const u16* __restrict__ B,
                                              void* __restrict__ Cp) {
  const int K = 1024;
  __shared__ __align__(16) u16 As[128 * 32];
  __shared__ __align__(16) u16 Bs[128 * 32];
  int tid = threadIdx.x;
  int lane = tid & 63, wid = tid >> 6;
  int wr = wid >> 1, wc = wid & 1;
  int m0 = blockIdx.y * 128, n0 = blockIdx.x * 128;
  int r = lane & 15, qq = lane >> 4;

  const u16* Ag0 = A + (size_t)(m0 + wid * 32 + (lane >> 2)) * K + (lane & 3) * 8;
  const u16* Bg0 = B + (size_t)(n0 + wid * 32 + (lane >> 2)) * K + (lane & 3) * 8;
  u16* Asl0 = As + (wid * 32) * 32;
  u16* Asl1 = As + (wid * 32 + 16) * 32;
  u16* Bsl0 = Bs + (wid * 32) * 32;
  u16* Bsl1 = Bs + (wid * 32 + 16) * 32;

  f32x4 acc[4][4] = {};

  for (int k0 = 0; k0 < K; k0 += 32) {
    gll16(Ag0 + k0, Asl0);
    gll16(Ag0 + 16 * K + k0, Asl1);
    gll16(Bg0 + k0, Bsl0);
    gll16(Bg0 + 16 * K + k0, Bsl1);
    __syncthreads();
    bf16x8 af[4], bfr[4];
#pragma unroll
    for (int m = 0; m < 4; ++m) af[m] = ld8(&As[(wr * 64 + m * 16 + r) * 32 + qq * 8]);
#pragma unroll
    for (int n = 0; n < 4; ++n) bfr[n] = ld8(&Bs[(wc * 64 + n * 16 + r) * 32 + qq * 8]);
#pragma unroll
    for (int m = 0; m < 4; ++m)
#pragma unroll
      for (int n = 0; n < 4; ++n) acc[m][n] = mfma16(af[m], bfr[n], acc[m][n]);
    __syncthreads();
  }

  if constexpr (EPI == 0) {
    u16* qkv = (u16*)Cp;
#pragma unroll
    for (int m = 0; m < 4; ++m) {
      int gr = m0 + wr * 64 + m * 16 + qq * 4;
      int b = gr >> 11, t0 = gr & 2047;
#pragma unroll
      for (int n = 0; n < 4; ++n) {
        int gc = n0 + wc * 64 + n * 16 + r;
        int which = gc >> 10, rem = gc & 1023;
        int hh = rem >> 6, d = rem & 63;
        u16* dst = qkv + (size_t)which * 8388608u +
                   ((size_t)((b * 16 + hh) * 2048 + t0)) * 64 + d;
#pragma unroll
        for (int i = 0; i < 4; ++i) dst[(size_t)i * 64] = f2b(acc[m][n][i]);
      }
    }
  } else {
    float* out = (float*)Cp;
#pragma unroll
    for (int m = 0; m < 4; ++m) {
      int gr = m0 + wr * 64 + m * 16 + qq * 4;
#pragma unroll
      for (int n = 0; n < 4; ++n) {
        int gc = n0 + wc * 64 + n * 16 + r;
#pragma unroll
        for (int i = 0; i < 4; ++i) out[(size_t)(gr + i) * 1024 + gc] = acc[m][n][i];
      }
    }
  }
}

// ---------------- flash attention v2 (pipelined) ----------------
// q,k,v [B*H][2048][64] bf16 -> y [B][2048][1024] bf16
// grid: x = 16 q-blocks of 128 rows (REVERSED: x=0 -> longest), y = B*H = 64.
// 4 waves x 32 q-rows. KV tile = 64 keys.
// Pipelining (T14 async-split): tile it+1's K and V are loaded global->reg
// DURING compute of tile it; written to (single-buffered) LDS after the next
// barrier. The __syncthreads vmcnt(0) drain then lands a full compute phase
// after issue -> global latency hidden. LDS stays 33 KB.
// NOTE: plain __launch_bounds__(256). Round-1's (256,4) forced VGPR to 64 and
// caused ~730 MB of scratch spill traffic per dispatch (WRITE_SIZE 16->245 MB).
// Round-0 measured 112 VGPR on this structure; staging regs add ~16-24.
// K LDS layout: row-major [64][64] with 16B-slot XOR swizzle (slot ^= row&7),
// achieved by XOR-ing the GLOBAL load offset and writing LDS linearly
// (ds_write_b128, conflict-free).
// V LDS: transposed [d=64][72] (padded) via reg-staged u16 writes.
// P LDS: per-wave [32][64] with slot XOR swizzle; packed bf16 via v_cvt_pk.
// Softmax VALU diet: per-lane partial row-sums (cross-lane reduce ONCE in the
// epilogue), causal mask only on diagonal tiles, rescale skipped when the
// running max did not grow (bit-identical: corr would be exactly 1).
__global__ __launch_bounds__(256) void k_attn(const u16* __restrict__ Qm,
                                              const u16* __restrict__ Km,
                                              const u16* __restrict__ Vm,
                                              u16* __restrict__ Y) {
  int bh = blockIdx.y;
  int b = bh >> 4, h = bh & 15;
  int qb0 = (gridDim.x - 1 - blockIdx.x) * 128;  // longest blocks first
  int tid = threadIdx.x, lane = tid & 63, w = tid >> 6;
  int r = lane & 15, qq = lane >> 4;
  __shared__ __align__(16) u16 Ks[64 * 64];     // [key][64], slots XOR-swizzled
  __shared__ __align__(16) u16 Vt[64 * 72];     // [d][key] padded rows
  __shared__ __align__(16) u16 Ps[4][32 * 64];  // per-wave P, slot-swizzled
  const size_t basekv = (size_t)bh * (2048 * 64);
  int q0w = qb0 + w * 32;  // this wave's first q row (global)

  // Q fragments: rows m*16+r, k-slices kc*32+qq*8
  bf16x8 qf[2][2];
#pragma unroll
  for (int m = 0; m < 2; ++m)
#pragma unroll
    for (int kc = 0; kc < 2; ++kc)
      qf[m][kc] = ld8(Qm + basekv + (size_t)(q0w + m * 16 + r) * 64 + kc * 32 + qq * 8);

  f32x4 acc[2][4] = {};
  float m_run[2][4], l_run[2][4];  // l_run: PER-LANE partial sums (keys this lane owns)
#pragma unroll
  for (int m = 0; m < 2; ++m)
#pragma unroll
    for (int i = 0; i < 4; ++i) { m_run[m][i] = -1e30f; l_run[m][i] = 0.f; }
  const float csc = 0.125f * 1.44269504089f;  // 1/sqrt(64) * log2(e)
  int ntiles = (qb0 >> 6) + 2;  // uniform across waves -> barriers safe

  // K staging: wave w stages tile rows w*16..w*16+15.
  // lane covers row w*16 + c*8 + krow, global 16B chunk (kchunk ^ krow)
  // (swizzle on the LOAD side; LDS write is LINEAR -> conflict-free b128).
  int krow = lane >> 3, kchunk = lane & 7;
  const u16* Kg = Km + basekv + (size_t)(w * 16 + krow) * 64 + ((kchunk ^ krow) * 8);
  const u16* Vg = Vm + basekv;

  u16x8 kreg[2], vreg[2];
  // prologue: load tile 0 into regs
  kreg[0] = *(const u16x8*)(Kg);
  kreg[1] = *(const u16x8*)(Kg + (size_t)8 * 64);
  {
    const u16* vp = Vg + (size_t)lane * 64;
    vreg[0] = *(const u16x8*)(vp + w * 8);
    vreg[1] = *(const u16x8*)(vp + (w + 4) * 8);
  }

  for (int it = 0; it < ntiles; ++it) {
    int j0 = it << 6;
    __syncthreads();  // all waves done reading previous tile; drains vmcnt -> regs ready
    // store staged tile it (K linear b128 writes; layout slot s holds chunk s^row&7)
    *(u16x8*)&Ks[(w * 16 + krow) * 64 + kchunk * 8] = kreg[0];
    *(u16x8*)&Ks[(w * 16 + 8 + krow) * 64 + kchunk * 8] = kreg[1];
#pragma unroll
    for (int jj = 0; jj < 8; ++jj) Vt[(w * 8 + jj) * 72 + lane] = vreg[0][jj];
#pragma unroll
    for (int jj = 0; jj < 8; ++jj) Vt[((w + 4) * 8 + jj) * 72 + lane] = vreg[1][jj];
    __syncthreads();  // LDS tile visible to all waves

    // prefetch tile it+1 global->reg (completes during compute below)
    if (it + 1 < ntiles) {
      size_t joff = (size_t)(j0 + 64) * 64;
      kreg[0] = *(const u16x8*)(Kg + joff);
      kreg[1] = *(const u16x8*)(Kg + joff + (size_t)8 * 64);
      const u16* vp = Vg + joff + (size_t)lane * 64;
      vreg[0] = *(const u16x8*)(vp + w * 8);
      vreg[1] = *(const u16x8*)(vp + (w + 4) * 8);
    }

    if (j0 <= q0w + 31) {  // wave-uniform: skip fully-masked tiles
      // S = Q K^T
      f32x4 s[2][4] = {};
#pragma unroll
      for (int nt = 0; nt < 4; ++nt)
#pragma unroll
        for (int kc = 0; kc < 2; ++kc) {
          bf16x8 kf = ld8(&Ks[(nt * 16 + r) * 64 + (((kc * 4 + qq) ^ (r & 7)) * 8)]);
#pragma unroll
          for (int m = 0; m < 2; ++m) s[m][nt] = mfma16(qf[m][kc], kf, s[m][nt]);
        }

      // scale (log2 domain); causal mask only on diagonal tiles (wave-uniform branch)
      bool nm = (j0 + 63 > q0w);
      if (nm) {
#pragma unroll
        for (int m = 0; m < 2; ++m)
#pragma unroll
          for (int nt = 0; nt < 4; ++nt)
#pragma unroll
            for (int i = 0; i < 4; ++i) {
              int qg = q0w + m * 16 + qq * 4 + i;
              int kg = j0 + nt * 16 + r;
              s[m][nt][i] = (kg <= qg) ? s[m][nt][i] * csc : -1e30f;
            }
      } else {
#pragma unroll
        for (int m = 0; m < 2; ++m)
#pragma unroll
          for (int nt = 0; nt < 4; ++nt)
#pragma unroll
            for (int i = 0; i < 4; ++i) s[m][nt][i] *= csc;
      }

      // row max: fold nt in-lane, then across the 16 r-lanes
      float tm[2][4];
#pragma unroll
      for (int m = 0; m < 2; ++m)
#pragma unroll
        for (int i = 0; i < 4; ++i)
          tm[m][i] = fmaxf(fmaxf(s[m][0][i], s[m][1][i]), fmaxf(s[m][2][i], s[m][3][i]));
#pragma unroll
      for (int d = 1; d < 16; d <<= 1)
#pragma unroll
        for (int m = 0; m < 2; ++m)
#pragma unroll
          for (int i = 0; i < 4; ++i) tm[m][i] = fmaxf(tm[m][i], __shfl_xor(tm[m][i], d));

      // rescale only if the running max grew (corr would be exactly 1 otherwise)
      int growf = 0;
#pragma unroll
      for (int m = 0; m < 2; ++m)
#pragma unroll
        for (int i = 0; i < 4; ++i) growf |= (tm[m][i] > m_run[m][i]) ? 1 : 0;
      if (__any(growf)) {
#pragma unroll
        for (int m = 0; m < 2; ++m)
#pragma unroll
          for (int i = 0; i < 4; ++i) {
            float mn = fmaxf(m_run[m][i], tm[m][i]);
            float corr = exp2f(m_run[m][i] - mn);
            m_run[m][i] = mn;
            l_run[m][i] *= corr;
#pragma unroll
            for (int n = 0; n < 4; ++n) acc[m][n][i] *= corr;
          }
      }

      // P = exp2(S - m); accumulate per-lane partial row sums (no cross-lane reduce)
#pragma unroll
      for (int m = 0; m < 2; ++m)
#pragma unroll
        for (int i = 0; i < 4; ++i) {
          float ls = 0.f;
#pragma unroll
          for (int nt = 0; nt < 4; ++nt) {
            float e = exp2f(s[m][nt][i] - m_run[m][i]);
            s[m][nt][i] = e;
            ls += e;
          }
          l_run[m][i] += ls;
        }

      // P -> per-wave LDS (swizzled) via packed bf16 cvt; wave-local fence; re-read
#pragma unroll
      for (int m = 0; m < 2; ++m)
#pragma unroll
        for (int nt = 0; nt < 4; ++nt) {
          int key = nt * 16 + r;
          int kb = key >> 3, kl = key & 7;
#pragma unroll
          for (int ii = 0; ii < 4; ii += 2) {
            u32 pk = pk2(s[m][nt][ii], s[m][nt][ii + 1]);
            int ql0 = m * 16 + qq * 4 + ii;
            int ql1 = ql0 + 1;
            Ps[w][ql0 * 64 + ((kb ^ (ql0 & 7)) * 8) + kl] = (u16)pk;
            Ps[w][ql1 * 64 + ((kb ^ (ql1 & 7)) * 8) + kl] = (u16)(pk >> 16);
          }
        }
      asm volatile("s_waitcnt lgkmcnt(0)" ::: "memory");  // wave-local LDS RAW fence

      bf16x8 vfr[4][2];
#pragma unroll
      for (int n = 0; n < 4; ++n)
#pragma unroll
        for (int kc = 0; kc < 2; ++kc)
          vfr[n][kc] = ld8(&Vt[(n * 16 + r) * 72 + kc * 32 + qq * 8]);
#pragma unroll
      for (int m = 0; m < 2; ++m) {
        bf16x8 pf[2];
#pragma unroll
        for (int kc = 0; kc < 2; ++kc)
          pf[kc] = ld8(&Ps[w][(m * 16 + r) * 64 + (((kc * 4 + qq) ^ (r & 7)) * 8)]);
#pragma unroll
        for (int n = 0; n < 4; ++n)
#pragma unroll
          for (int kc = 0; kc < 2; ++kc)
            acc[m][n] = mfma16(pf[kc], vfr[n][kc], acc[m][n]);
      }
    }
  }

  // epilogue: reduce per-lane partial sums across the 16 r-lanes (once)
#pragma unroll
  for (int d = 1; d < 16; d <<= 1)
#pragma unroll
    for (int m = 0; m < 2; ++m)
#pragma unroll
      for (int i = 0; i < 4; ++i) l_run[m][i] += __shfl_xor(l_run[m][i], d);

  float inv[2][4];
#pragma unroll
  for (int m = 0; m < 2; ++m)
#pragma unroll
    for (int i = 0; i < 4; ++i) inv[m][i] = 1.0f / l_run[m][i];
#pragma unroll
  for (int m = 0; m < 2; ++m)
#pragma unroll
    for (int n = 0; n < 4; ++n)
#pragma unroll
      for (int i = 0; i < 4; ++i)
        Y[((size_t)(b * 2048 + q0w + m * 16 + qq * 4 + i)) * 1024 + h * 64 + n * 16 + r] =
            f2b(acc[m][n][i] * inv[m][i]);
}

// ---------------- launch ----------------
extern "C" void kernel_launch(void* const* d_in, const int* in_sizes, int n_in,
                              void* d_out, int out_size, void* d_ws, size_t ws_size,
                              hipStream_t stream) {
  const float* x = (const float*)d_in[0];       // [4,2048,1024]
  const float* w_attn = (const float*)d_in[1];  // [1024,3072]
  const float* w_o = (const float*)d_in[2];     // [1024,1024]
  float* out = (float*)d_out;                   // [4,2048,1024]

  char* ws = (char*)d_ws;
  u16* xb = (u16*)(ws + 0);                    // [8192][1024]        16,777,216 B
  u16* watT = (u16*)(ws + 16777216);           // [3072][1024]         6,291,456 B
  u16* woT = (u16*)(ws + 23068672);            // [1024][1024]         2,097,152 B
  u16* qb = (u16*)(ws + 25165824);             // q [4][16][2048][64] 16,777,216 B
  u16* kb = (u16*)(ws + 41943040);             // k                   16,777,216 B
  u16* vb = (u16*)(ws + 58720256);             // v                   16,777,216 B
  u16* yb = (u16*)(ws + 75497472);             // y [4][2048][1024]   16,777,216 B

  k_cvt<<<2048, 256, 0, stream>>>(x, xb, 8192 * 1024 / 4);
  k_tr<<<dim3(3072 / 32, 1024 / 32), dim3(32, 8), 0, stream>>>(w_attn, watT, 1024, 3072);
  k_tr<<<dim3(1024 / 32, 1024 / 32), dim3(32, 8), 0, stream>>>(w_o, woT, 1024, 1024);
  k_gemm<0><<<dim3(24, 64), 256, 0, stream>>>(xb, watT, (void*)qb);
  k_attn<<<dim3(16, 64), 256, 0, stream>>>(qb, kb, vb, yb);
  k_gemm<1><<<dim3(8, 64), 256, 0, stream>>>(yb, woT, (void*)out);
}